// Round 2
// baseline (1366.908 us; speedup 1.0000x reference)
//
#include <hip/hip_runtime.h>
#include <stdint.h>

typedef __attribute__((ext_vector_type(8))) short bf16x8;
typedef __attribute__((ext_vector_type(4))) float f32x4;
typedef __attribute__((ext_vector_type(8))) unsigned short us8;

__device__ __forceinline__ unsigned short f2bf(float f) {
  unsigned u = __builtin_bit_cast(unsigned, f);
  return (unsigned short)((u + 0x7FFFu + ((u >> 16) & 1u)) >> 16);
}

#define GLD16(g, l)                                                            \
  __builtin_amdgcn_global_load_lds(                                            \
      (const __attribute__((address_space(1))) unsigned int*)(g),              \
      (__attribute__((address_space(3))) unsigned int*)(l), 16, 0, 0)

// ---------------------------------------------------------------------------
// prep_w: Wq/Wk/Wv [256][256][3][3] fp32 -> Wt[kh][kw][cg=768][ci=256] bf16
// ---------------------------------------------------------------------------
__global__ void prep_w(const float* __restrict__ wq, const float* __restrict__ wk,
                       const float* __restrict__ wv, unsigned short* __restrict__ wt) {
  int idx = blockIdx.x * 256 + threadIdx.x;  // exactly 1769472 threads
  int ci = idx & 255;
  int t = idx >> 8;  // khw*768 + cg
  int cg = t % 768;
  int khw = t / 768;
  int kh = khw / 3, kw = khw % 3;
  int conv = cg >> 8, cl = cg & 255;
  const float* src = conv == 0 ? wq : (conv == 1 ? wk : wv);
  wt[idx] = f2bf(src[((cl * 256 + ci) * 3 + kh) * 3 + kw]);
}

// ---------------------------------------------------------------------------
// prep_x: x [16][256][128][128] fp32 -> x_t[b][h][w][ci] bf16 (LDS transpose)
// grid (4 ci-tiles, 128 h, 16 b), 256 threads
// ---------------------------------------------------------------------------
__global__ void prep_x(const float* __restrict__ x, unsigned short* __restrict__ xt) {
  __shared__ unsigned short xs[64][130];
  const int tid = threadIdx.x;
  const int ci0 = blockIdx.x * 64;
  const int h = blockIdx.y;
  const int b = blockIdx.z;
#pragma unroll
  for (int i = 0; i < 8; ++i) {
    int f = tid + 256 * i;          // 2048 float4s = [64 ci][128 w]
    int r = f >> 5, w4 = f & 31;
    f32x4 v = *(const f32x4*)(x + (((size_t)(b * 256 + ci0 + r) * 128 + h) * 128 + w4 * 4));
    xs[r][w4 * 4 + 0] = f2bf(v[0]);
    xs[r][w4 * 4 + 1] = f2bf(v[1]);
    xs[r][w4 * 4 + 2] = f2bf(v[2]);
    xs[r][w4 * 4 + 3] = f2bf(v[3]);
  }
  __syncthreads();
#pragma unroll
  for (int i = 0; i < 4; ++i) {
    int q = tid + 256 * i;          // 1024 chunks of 8 ushorts: [128 w][8 jc]
    int w = q >> 3, jc = q & 7;
    us8 o;
#pragma unroll
    for (int j = 0; j < 8; ++j) o[j] = xs[jc * 8 + j][w];
    *(us8*)(xt + ((size_t)(b * 128 + h) * 128 + w) * 256 + ci0 + jc * 8) = o;
  }
}

// ---------------------------------------------------------------------------
// conv_qkv: implicit GEMM. M=768 (q|k|v stacked), N = one row (b,h): 128 w,
// K = 2304 as 3(kh) x 4(ci-chunk 64) x 3(kw). 128x128 tile, 4 waves (2x2),
// mfma 16x16x32 bf16. LDS: As 48K (3 kw x [128c][64ci]) + Xs 16K ([128w][64ci]),
// both XOR-swizzled; staged via global_load_lds w/ pre-swizzled source (m173).
// grid (6 ctiles, 128 h, 16 b), 256 threads. 64 KiB LDS -> 2 blocks/CU.
// ---------------------------------------------------------------------------
__global__ __launch_bounds__(256, 2) void conv_qkv(
    const unsigned short* __restrict__ xt, const unsigned short* __restrict__ wt,
    const float* __restrict__ bq, const float* __restrict__ bk,
    const float* __restrict__ bv, unsigned short* __restrict__ qkout,
    unsigned short* __restrict__ vout) {
  __shared__ unsigned short As[3 * 8192];
  __shared__ unsigned short Xs[8192];
  const int tid = threadIdx.x;
  const int lane = tid & 63;
  const int wid = tid >> 6;
  const int wm = wid >> 1, wn = wid & 1;
  const int l15 = lane & 15, l4 = lane >> 4;
  const int ct = blockIdx.x;
  const int h = blockIdx.y;
  const int b = blockIdx.z;
  const int cg0 = ct * 128;

  f32x4 acc[4][4] = {};

  for (int kh = 0; kh < 3; ++kh) {
    const int hs = h + kh - 1;
    if (hs < 0 || hs > 127) continue;  // SAME padding in h: zero contribution
    const unsigned short* xrow = xt + (size_t)(b * 128 + hs) * 128 * 256;
    const unsigned short* wbase = wt + (size_t)(kh * 3) * 768 * 256;
    for (int ch = 0; ch < 4; ++ch) {
      const int ci0 = ch * 64;
      __syncthreads();  // previous compute done before LDS overwrite
      // stage X tile [128 w][64 ci] (16 KB): 16 wave-loads, 4 per wave
#pragma unroll
      for (int ii = 0; ii < 4; ++ii) {
        int i = wid * 4 + ii;
        int cidx = i * 64 + lane;       // 16B-chunk index 0..1023
        int w = cidx >> 3, j = cidx & 7;
        int jg = j ^ (w & 7);           // inverse swizzle on global source
        GLD16(xrow + w * 256 + ci0 + jg * 8, (char*)Xs + i * 1024);
      }
      // stage A tiles: 3 kw x [128 c][64 ci] (48 KB): 48 wave-loads, 12/wave
#pragma unroll
      for (int ii = 0; ii < 12; ++ii) {
        int i = wid * 12 + ii;
        int cidx = i * 64 + lane;       // 0..3071
        int kw = cidx >> 10, cc = cidx & 1023;
        int row = cc >> 3, j = cc & 7;
        int jg = j ^ (row & 7);
        GLD16(wbase + (size_t)(kw * 768 + cg0 + row) * 256 + ci0 + jg * 8,
              (char*)As + i * 1024);
      }
      __syncthreads();
#pragma unroll
      for (int kw = 0; kw < 3; ++kw) {
#pragma unroll
        for (int kp = 0; kp < 2; ++kp) {
          const int ko = (kp * 32 + l4 * 8) * 2;  // k-slice byte offset
          bf16x8 a[4], bb[4];
#pragma unroll
          for (int mf = 0; mf < 4; ++mf) {
            int row = wm * 64 + mf * 16 + l15;
            a[mf] = *(const bf16x8*)((const char*)As + kw * 16384 + row * 128 +
                                     (ko ^ ((row & 7) << 4)));
          }
#pragma unroll
          for (int nf = 0; nf < 4; ++nf) {
            int w = wn * 64 + nf * 16 + l15;
            int rr = w + kw - 1;                      // shifted source column
            int rc = rr < 0 ? 0 : (rr > 127 ? 127 : rr);
            bf16x8 t = *(const bf16x8*)((const char*)Xs + rc * 128 +
                                        (ko ^ ((rc & 7) << 4)));
            if (rr != rc) t = bf16x8{0, 0, 0, 0, 0, 0, 0, 0};  // SAME pad in w
            bb[nf] = t;
          }
#pragma unroll
          for (int mf = 0; mf < 4; ++mf)
#pragma unroll
            for (int nf = 0; nf < 4; ++nf)
              acc[mf][nf] = __builtin_amdgcn_mfma_f32_16x16x32_bf16(
                  a[mf], bb[nf], acc[mf][nf], 0, 0, 0);
        }
      }
    }
  }

  // epilogue: bias + cast bf16.
  // ct 0,1 -> q at byte 0 of each 64KiB d_out region; ct 2,3 -> k at byte 32768
  // of the same region; ct 4,5 -> v in ws. q,k are fully consumed into LDS by
  // attn before its output stores overwrite the region.
  const int conv = ct >> 1;
  const float* bias = conv == 0 ? bq : (conv == 1 ? bk : bv);
  unsigned short* outp = conv == 0 ? qkout : (conv == 1 ? qkout + 16384 : vout);
  const int per_bc = conv == 2 ? 16384 : 32768;
#pragma unroll
  for (int mf = 0; mf < 4; ++mf)
#pragma unroll
    for (int r = 0; r < 4; ++r) {
      int crow = (ct & 1) * 128 + wm * 64 + mf * 16 + l4 * 4 + r;  // c in conv
      float bia = bias[crow];
      unsigned short* dst = outp + (size_t)(b * 256 + crow) * per_bc + h * 128;
#pragma unroll
      for (int nf = 0; nf < 4; ++nf) {
        int w = wn * 64 + nf * 16 + l15;
        dst[w] = f2bf(acc[mf][nf][r] + bia);
      }
    }
}

// ---------------------------------------------------------------------------
// attn: one block per (b,c). LDS: qs (q then P), ks (k then v^T). 4 waves,
// each owns 32 h-rows. QK^T -> in-register wave-parallel softmax -> PV.
// v^T built via per-lane register transpose + ds_write_b128 (chunk swizzle
// (w&7)^((w>>3)&7) gives >=8 distinct banks on both write and read sides).
// grid (256 c, 16 b), 256 threads. 64 KiB LDS -> 2 blocks/CU.
// ---------------------------------------------------------------------------
__global__ __launch_bounds__(256, 2) void attn_kernel(
    const unsigned short* qkbuf, const unsigned short* __restrict__ vbuf,
    float* out) {
  __shared__ unsigned short qs[16384];
  __shared__ unsigned short ks[16384];
  const int tid = threadIdx.x;
  const int lane = tid & 63;
  const int wid = tid >> 6;
  const int l15 = lane & 15, l4 = lane >> 4;
  const int bc = blockIdx.y * 256 + blockIdx.x;

  // issue v loads early (consumed after QK^T) to hide HBM latency.
  // lane holds v[g0+i][s*8..s*8+7] for i=0..7: 8 consecutive g rows, one
  // 16B w-chunk -> transpose is a pure per-lane register gather.
  const unsigned short* vsrc = vbuf + (size_t)bc * 16384;
  const int vs = tid & 15;           // w-chunk
  const int vg0 = (tid >> 4) * 8;    // first g row
  uint4 vreg[8];
#pragma unroll
  for (int i = 0; i < 8; ++i)
    vreg[i] = *(const uint4*)(vsrc + (vg0 + i) * 128 + vs * 8);

  // stage q,k (swizzled rows of 256B = 16 chunks, XOR low 3 chunk bits)
  const unsigned short* qsrc = qkbuf + (size_t)bc * 32768;
  const unsigned short* ksrc = qsrc + 16384;
#pragma unroll
  for (int ii = 0; ii < 8; ++ii) {
    int i = wid * 8 + ii;
    int t2 = i * 64 + lane;
    int row = t2 >> 4, s = t2 & 15;
    int sg = s ^ (row & 7);
    GLD16(qsrc + row * 128 + sg * 8, (char*)qs + i * 1024);
    GLD16(ksrc + row * 128 + sg * 8, (char*)ks + i * 1024);
  }
  __syncthreads();

  // QK^T: scores[h][g] = sum_w q[h][w] k[g][w]
  f32x4 acc[2][8] = {};
#pragma unroll
  for (int kp = 0; kp < 4; ++kp) {
    int ko = (kp * 32 + l4 * 8) * 2;
    bf16x8 a[2], bb[8];
#pragma unroll
    for (int mf = 0; mf < 2; ++mf) {
      int hh = wid * 32 + mf * 16 + l15;
      a[mf] = *(const bf16x8*)((const char*)qs + hh * 256 + (ko ^ ((hh & 7) << 4)));
    }
#pragma unroll
    for (int nf = 0; nf < 8; ++nf) {
      int g = nf * 16 + l15;
      bb[nf] = *(const bf16x8*)((const char*)ks + g * 256 + (ko ^ ((g & 7) << 4)));
    }
#pragma unroll
    for (int mf = 0; mf < 2; ++mf)
#pragma unroll
      for (int nf = 0; nf < 8; ++nf)
        acc[mf][nf] =
            __builtin_amdgcn_mfma_f32_16x16x32_bf16(a[mf], bb[nf], acc[mf][nf], 0, 0, 0);
  }
  __syncthreads();  // all waves done reading qs/ks before overwrite

  // scatter v^T into ks: vt row w holds g contiguous. 8 x ds_write_b128/lane.
#pragma unroll
  for (int j = 0; j < 8; ++j) {
    int w = vs * 8 + j;
    us8 o;
#pragma unroll
    for (int i = 0; i < 8; ++i) o[i] = ((const unsigned short*)&vreg[i])[j];
    int chunk = (vg0 >> 3) ^ (w & 7) ^ ((w >> 3) & 7);
    *(us8*)((char*)ks + w * 256 + (chunk << 4)) = o;
  }

  // softmax over g (row-wise), scale 1/sqrt(W=128); P -> bf16 into qs
  const float SC = 0.088388347648318447f;
#pragma unroll
  for (int mf = 0; mf < 2; ++mf)
#pragma unroll
    for (int nf = 0; nf < 8; ++nf) acc[mf][nf] *= SC;
#pragma unroll
  for (int mf = 0; mf < 2; ++mf) {
#pragma unroll
    for (int r = 0; r < 4; ++r) {
      float m = acc[mf][0][r];
#pragma unroll
      for (int nf = 1; nf < 8; ++nf) m = fmaxf(m, acc[mf][nf][r]);
      m = fmaxf(m, __shfl_xor(m, 1));
      m = fmaxf(m, __shfl_xor(m, 2));
      m = fmaxf(m, __shfl_xor(m, 4));
      m = fmaxf(m, __shfl_xor(m, 8));
      float p[8], ssum = 0.f;
#pragma unroll
      for (int nf = 0; nf < 8; ++nf) {
        p[nf] = __expf(acc[mf][nf][r] - m);
        ssum += p[nf];
      }
      ssum += __shfl_xor(ssum, 1);
      ssum += __shfl_xor(ssum, 2);
      ssum += __shfl_xor(ssum, 4);
      ssum += __shfl_xor(ssum, 8);
      float inv = 1.f / ssum;
      int hh = wid * 32 + mf * 16 + l4 * 4 + r;
      int swz = (hh & 7) << 4;
#pragma unroll
      for (int nf = 0; nf < 8; ++nf) {
        int g = nf * 16 + l15;
        *(unsigned short*)((char*)qs + hh * 256 + ((2 * g) ^ swz)) = f2bf(p[nf] * inv);
      }
    }
  }
  __syncthreads();

  // PV: out[h][w] = sum_g P[h][g] v[g][w]
  f32x4 o[2][8] = {};
#pragma unroll
  for (int kp = 0; kp < 4; ++kp) {
    int ko = (kp * 32 + l4 * 8) * 2;
    bf16x8 pa[2], vb[8];
#pragma unroll
    for (int mf = 0; mf < 2; ++mf) {
      int hh = wid * 32 + mf * 16 + l15;
      pa[mf] = *(const bf16x8*)((const char*)qs + hh * 256 + (ko ^ ((hh & 7) << 4)));
    }
#pragma unroll
    for (int nf = 0; nf < 8; ++nf) {
      int w = nf * 16 + l15;
      int chunk = (ko >> 4) ^ (w & 7) ^ ((w >> 3) & 7);
      vb[nf] = *(const bf16x8*)((const char*)ks + w * 256 + (chunk << 4));
    }
#pragma unroll
    for (int mf = 0; mf < 2; ++mf)
#pragma unroll
      for (int nf = 0; nf < 8; ++nf)
        o[mf][nf] =
            __builtin_amdgcn_mfma_f32_16x16x32_bf16(pa[mf], vb[nf], o[mf][nf], 0, 0, 0);
  }
  float* ob = out + (size_t)bc * 16384;
#pragma unroll
  for (int mf = 0; mf < 2; ++mf)
#pragma unroll
    for (int r = 0; r < 4; ++r) {
      int hh = wid * 32 + mf * 16 + l4 * 4 + r;
#pragma unroll
      for (int nf = 0; nf < 8; ++nf) {
        int w = nf * 16 + l15;
        ob[hh * 128 + w] = o[mf][nf][r];
      }
    }
}

// ---------------------------------------------------------------------------
extern "C" void kernel_launch(void* const* d_in, const int* in_sizes, int n_in,
                              void* d_out, int out_size, void* d_ws, size_t ws_size,
                              hipStream_t stream) {
  const float* x = (const float*)d_in[0];
  const float* wq = (const float*)d_in[1];
  const float* bq = (const float*)d_in[2];
  const float* wk = (const float*)d_in[3];
  const float* bk = (const float*)d_in[4];
  const float* wv = (const float*)d_in[5];
  const float* bv = (const float*)d_in[6];

  // ws layout: x_t (128 MiB) | Wt (3.375 MiB) | v (128 MiB)  => ~259.4 MiB.
  // q,k (bf16) live inside d_out: each (b,c) region is 64 KiB f32; q occupies
  // bytes [0,32768), k bytes [32768,65536) until attn consumes them.
  char* ws = (char*)d_ws;
  unsigned short* xt = (unsigned short*)ws;
  unsigned short* wt = (unsigned short*)(ws + 134217728);
  unsigned short* vbuf = (unsigned short*)(ws + 134217728 + 3538944);

  prep_w<<<6912, 256, 0, stream>>>(wq, wk, wv, wt);
  prep_x<<<dim3(4, 128, 16), 256, 0, stream>>>(x, xt);
  conv_qkv<<<dim3(6, 128, 16), 256, 0, stream>>>(
      xt, wt, bq, bk, bv, (unsigned short*)d_out, vbuf);
  attn_kernel<<<dim3(256, 16), 256, 0, stream>>>(
      (const unsigned short*)d_out, vbuf, (float*)d_out);
}

// Round 4
// 1276.229 us; speedup vs baseline: 1.0711x; 1.0711x over previous
//
#include <hip/hip_runtime.h>
#include <stdint.h>

typedef __attribute__((ext_vector_type(8))) short bf16x8;
typedef __attribute__((ext_vector_type(4))) float f32x4;
typedef __attribute__((ext_vector_type(8))) unsigned short us8;

__device__ __forceinline__ unsigned short f2bf(float f) {
  unsigned u = __builtin_bit_cast(unsigned, f);
  return (unsigned short)((u + 0x7FFFu + ((u >> 16) & 1u)) >> 16);
}

#define GLD16(g, l)                                                            \
  __builtin_amdgcn_global_load_lds(                                            \
      (const __attribute__((address_space(1))) unsigned int*)(g),              \
      (__attribute__((address_space(3))) unsigned int*)(l), 16, 0, 0)

#define SCHED0() __builtin_amdgcn_sched_barrier(0)
#define SBAR()                                                                 \
  do {                                                                         \
    SCHED0();                                                                  \
    __builtin_amdgcn_s_barrier();                                              \
    SCHED0();                                                                  \
  } while (0)
#define WAITVM(n)                                                              \
  do {                                                                         \
    asm volatile("s_waitcnt vmcnt(" #n ")" ::: "memory");                      \
    SCHED0();                                                                  \
  } while (0)

// ---------------------------------------------------------------------------
// prep_w: Wq/Wk/Wv [256][256][3][3] fp32 -> Wt[kh][kw][cg=768][ci=256] bf16
// ---------------------------------------------------------------------------
__global__ void prep_w(const float* __restrict__ wq, const float* __restrict__ wk,
                       const float* __restrict__ wv, unsigned short* __restrict__ wt) {
  int idx = blockIdx.x * 256 + threadIdx.x;  // exactly 1769472 threads
  int ci = idx & 255;
  int t = idx >> 8;  // khw*768 + cg
  int cg = t % 768;
  int khw = t / 768;
  int kh = khw / 3, kw = khw % 3;
  int conv = cg >> 8, cl = cg & 255;
  const float* src = conv == 0 ? wq : (conv == 1 ? wk : wv);
  wt[idx] = f2bf(src[((cl * 256 + ci) * 3 + kh) * 3 + kw]);
}

// ---------------------------------------------------------------------------
// prep_x: x [16][256][128][128] fp32 -> x_t[b][h][w][ci] bf16.
// No LDS: strided f32x4 loads + in-register 8ci x 4w transpose + us8 stores.
// grid (4 ci-tiles, 128 h, 16 b), 256 threads.
// ---------------------------------------------------------------------------
__global__ void prep_x(const float* __restrict__ x, unsigned short* __restrict__ xt) {
  const int tid = threadIdx.x;
  const int jc = tid >> 5, wg = tid & 31;  // wg fast => coalesced loads
  const int ci0 = blockIdx.x * 64;
  const int h = blockIdx.y;
  const int b = blockIdx.z;
  f32x4 v[8];
#pragma unroll
  for (int j = 0; j < 8; ++j)
    v[j] = *(const f32x4*)(x + (((size_t)(b * 256 + ci0 + jc * 8 + j)) * 128 + h) * 128 +
                           wg * 4);
  unsigned short* dst = xt + ((size_t)(b * 128 + h) * 128) * 256 + ci0 + jc * 8;
#pragma unroll
  for (int m = 0; m < 4; ++m) {
    us8 o;
#pragma unroll
    for (int j = 0; j < 8; ++j) o[j] = f2bf(v[j][m]);
    *(us8*)(dst + (wg * 4 + m) * 256) = o;
  }
}

// ---------------------------------------------------------------------------
// conv_qkv: implicit GEMM, BM=256 (one conv: ct=0 q, 1 k, 2 v), BN=128 (one
// (b,h) row), K = 3(kh) x 4(ci64) x 3(kw) x 2(K32). 4 waves as 2Mx2N, each
// 128x64 (8x4 fragments) -> LDS-read cost 0.375 KB/MFMA (cap ~81% MfmaUtil).
// LDS: Xs 16K + As 2-slot 64K = 80K -> 2 blocks/CU. Counted-vmcnt schedule:
// issue X,A0,A1; vm(8)+bar; kw0; bar; issue A2->slot0; vm(8)+bar; kw1;
// vm(0)+bar; kw2. XOR-swizzled tiles, pre-swizzled global source (m173).
// grid 6144 = 3ct x 128h x 16b, XCD-chunked bijective swizzle, ct minor.
// ---------------------------------------------------------------------------
__global__ __launch_bounds__(256, 2) void conv_qkv(
    const unsigned short* __restrict__ xt, const unsigned short* __restrict__ wt,
    const float* __restrict__ bq, const float* __restrict__ bk,
    const float* __restrict__ bv, unsigned short* __restrict__ qkout,
    unsigned short* __restrict__ vout) {
  __shared__ unsigned short Xs[8192];
  __shared__ unsigned short As[2][16384];
  const int tid = threadIdx.x;
  const int lane = tid & 63;
  const int wid = tid >> 6;
  const int wm = wid >> 1, wn = wid & 1;
  const int l15 = lane & 15, l4 = lane >> 4;
  // XCD-chunked swizzle: hw block n -> XCD n%8; give each XCD a contiguous
  // logical range of 768 (= 256 (b,h) x 3 ct, ct minor => X-tile L2 reuse).
  const int n = blockIdx.x;
  const int lg = (n & 7) * 768 + (n >> 3);
  const int ct = lg % 3;
  const int rest = lg / 3;
  const int h = rest & 127, b = rest >> 7;
  const int cg0 = ct * 256;

  f32x4 acc[8][4] = {};

  auto stageX = [&](const unsigned short* xsrc) {
#pragma unroll
    for (int ii = 0; ii < 4; ++ii) {
      int i = wid * 4 + ii;
      int cidx = i * 64 + lane;  // 16B chunk in [128 w][8 j]
      int w = cidx >> 3, j = cidx & 7;
      GLD16(xsrc + w * 256 + (j ^ (w & 7)) * 8, (char*)Xs + i * 1024);
    }
  };
  auto stageA = [&](const unsigned short* asrc, unsigned short* slot) {
#pragma unroll
    for (int ii = 0; ii < 8; ++ii) {
      int i = wid * 8 + ii;
      int cidx = i * 64 + lane;  // 16B chunk in [256 row][8 j]
      int row = cidx >> 3, j = cidx & 7;
      GLD16(asrc + row * 256 + (j ^ (row & 7)) * 8, (char*)slot + i * 1024);
    }
  };
  auto compute = [&](const unsigned short* slot, int kw) {
    __builtin_amdgcn_s_setprio(1);
#pragma unroll
    for (int kp = 0; kp < 2; ++kp) {
      const int ko = (kp * 32 + l4 * 8) * 2;
      bf16x8 bfr[4];
#pragma unroll
      for (int nf = 0; nf < 4; ++nf) {
        int w = wn * 64 + nf * 16 + l15;
        int rr = w + kw - 1;  // shifted source column (SAME pad in w)
        int rc = rr < 0 ? 0 : (rr > 127 ? 127 : rr);
        bf16x8 t =
            *(const bf16x8*)((const char*)Xs + rc * 128 + (ko ^ ((rc & 7) << 4)));
        if (rr != rc) t = (bf16x8){0, 0, 0, 0, 0, 0, 0, 0};
        bfr[nf] = t;
      }
#pragma unroll
      for (int mf = 0; mf < 8; ++mf) {
        int row = wm * 128 + mf * 16 + l15;
        bf16x8 af =
            *(const bf16x8*)((const char*)slot + row * 128 + (ko ^ ((row & 7) << 4)));
#pragma unroll
        for (int nf = 0; nf < 4; ++nf)
          acc[mf][nf] = __builtin_amdgcn_mfma_f32_16x16x32_bf16(af, bfr[nf],
                                                               acc[mf][nf], 0, 0, 0);
      }
    }
    __builtin_amdgcn_s_setprio(0);
  };

  for (int kh = 0; kh < 3; ++kh) {
    const int hs = h + kh - 1;
    if (hs < 0 || hs > 127) continue;  // SAME padding in h (block-uniform)
    const unsigned short* xrow = xt + (size_t)(b * 128 + hs) * 32768;
    const unsigned short* wk0 = wt + ((size_t)(kh * 3) * 768 + cg0) * 256;
#pragma unroll 1
    for (int ch = 0; ch < 4; ++ch) {
      const int ci0 = ch * 64;
      SBAR();  // previous stage's reads complete -> safe to overwrite
      stageX(xrow + ci0);
      stageA(wk0 + ci0, As[0]);              // kw=0
      stageA(wk0 + 196608 + ci0, As[1]);     // kw=1 (768*256)
      WAITVM(8);                             // X + A0 landed (A1 in flight)
      SBAR();
      compute(As[0], 0);
      SBAR();                                // all waves done reading slot0
      stageA(wk0 + 393216 + ci0, As[0]);     // kw=2 -> slot0
      WAITVM(8);                             // A1 landed (A2 is the newest 8)
      SBAR();
      compute(As[1], 1);
      WAITVM(0);                             // A2 landed
      SBAR();
      compute(As[0], 2);
    }
  }

  // epilogue: bias + cast bf16. ct0 -> q at byte 0 of each 64KiB d_out region;
  // ct1 -> k at short-offset 16384; ct2 -> v in ws.
  const float* bias = ct == 0 ? bq : (ct == 1 ? bk : bv);
  unsigned short* outp = ct == 0 ? qkout : (ct == 1 ? qkout + 16384 : vout);
  const int per_bc = ct == 2 ? 16384 : 32768;
#pragma unroll
  for (int mf = 0; mf < 8; ++mf)
#pragma unroll
    for (int r = 0; r < 4; ++r) {
      int crow = wm * 128 + mf * 16 + l4 * 4 + r;  // channel within this conv
      float bia = bias[crow];
      unsigned short* dst = outp + (size_t)(b * 256 + crow) * per_bc + h * 128;
#pragma unroll
      for (int nf = 0; nf < 4; ++nf) {
        int w = wn * 64 + nf * 16 + l15;
        dst[w] = f2bf(acc[mf][nf][r] + bia);
      }
    }
}

// ---------------------------------------------------------------------------
// attn: one block per (b,c). LDS: qs (q then P), ks (k then v^T). 4 waves,
// each owns 32 h-rows. QK^T -> in-register wave-parallel softmax -> PV.
// (unchanged from the passing round-2 version)
// ---------------------------------------------------------------------------
__global__ __launch_bounds__(256, 2) void attn_kernel(
    const unsigned short* qkbuf, const unsigned short* __restrict__ vbuf,
    float* out) {
  __shared__ unsigned short qs[16384];
  __shared__ unsigned short ks[16384];
  const int tid = threadIdx.x;
  const int lane = tid & 63;
  const int wid = tid >> 6;
  const int l15 = lane & 15, l4 = lane >> 4;
  const int bc = blockIdx.y * 256 + blockIdx.x;

  const unsigned short* vsrc = vbuf + (size_t)bc * 16384;
  const int vs = tid & 15;         // w-chunk
  const int vg0 = (tid >> 4) * 8;  // first g row
  uint4 vreg[8];
#pragma unroll
  for (int i = 0; i < 8; ++i)
    vreg[i] = *(const uint4*)(vsrc + (vg0 + i) * 128 + vs * 8);

  const unsigned short* qsrc = qkbuf + (size_t)bc * 32768;
  const unsigned short* ksrc = qsrc + 16384;
#pragma unroll
  for (int ii = 0; ii < 8; ++ii) {
    int i = wid * 8 + ii;
    int t2 = i * 64 + lane;
    int row = t2 >> 4, s = t2 & 15;
    int sg = s ^ (row & 7);
    GLD16(qsrc + row * 128 + sg * 8, (char*)qs + i * 1024);
    GLD16(ksrc + row * 128 + sg * 8, (char*)ks + i * 1024);
  }
  __syncthreads();

  f32x4 acc[2][8] = {};
#pragma unroll
  for (int kp = 0; kp < 4; ++kp) {
    int ko = (kp * 32 + l4 * 8) * 2;
    bf16x8 a[2], bb[8];
#pragma unroll
    for (int mf = 0; mf < 2; ++mf) {
      int hh = wid * 32 + mf * 16 + l15;
      a[mf] = *(const bf16x8*)((const char*)qs + hh * 256 + (ko ^ ((hh & 7) << 4)));
    }
#pragma unroll
    for (int nf = 0; nf < 8; ++nf) {
      int g = nf * 16 + l15;
      bb[nf] = *(const bf16x8*)((const char*)ks + g * 256 + (ko ^ ((g & 7) << 4)));
    }
#pragma unroll
    for (int mf = 0; mf < 2; ++mf)
#pragma unroll
      for (int nf = 0; nf < 8; ++nf)
        acc[mf][nf] =
            __builtin_amdgcn_mfma_f32_16x16x32_bf16(a[mf], bb[nf], acc[mf][nf], 0, 0, 0);
  }
  __syncthreads();

#pragma unroll
  for (int j = 0; j < 8; ++j) {
    int w = vs * 8 + j;
    us8 o;
#pragma unroll
    for (int i = 0; i < 8; ++i) o[i] = ((const unsigned short*)&vreg[i])[j];
    int chunk = (vg0 >> 3) ^ (w & 7) ^ ((w >> 3) & 7);
    *(us8*)((char*)ks + w * 256 + (chunk << 4)) = o;
  }

  const float SC = 0.088388347648318447f;
#pragma unroll
  for (int mf = 0; mf < 2; ++mf)
#pragma unroll
    for (int nf = 0; nf < 8; ++nf) acc[mf][nf] *= SC;
#pragma unroll
  for (int mf = 0; mf < 2; ++mf) {
#pragma unroll
    for (int r = 0; r < 4; ++r) {
      float m = acc[mf][0][r];
#pragma unroll
      for (int nf = 1; nf < 8; ++nf) m = fmaxf(m, acc[mf][nf][r]);
      m = fmaxf(m, __shfl_xor(m, 1));
      m = fmaxf(m, __shfl_xor(m, 2));
      m = fmaxf(m, __shfl_xor(m, 4));
      m = fmaxf(m, __shfl_xor(m, 8));
      float p[8], ssum = 0.f;
#pragma unroll
      for (int nf = 0; nf < 8; ++nf) {
        p[nf] = __expf(acc[mf][nf][r] - m);
        ssum += p[nf];
      }
      ssum += __shfl_xor(ssum, 1);
      ssum += __shfl_xor(ssum, 2);
      ssum += __shfl_xor(ssum, 4);
      ssum += __shfl_xor(ssum, 8);
      float inv = 1.f / ssum;
      int hh = wid * 32 + mf * 16 + l4 * 4 + r;
      int swz = (hh & 7) << 4;
#pragma unroll
      for (int nf = 0; nf < 8; ++nf) {
        int g = nf * 16 + l15;
        *(unsigned short*)((char*)qs + hh * 256 + ((2 * g) ^ swz)) = f2bf(p[nf] * inv);
      }
    }
  }
  __syncthreads();

  f32x4 o[2][8] = {};
#pragma unroll
  for (int kp = 0; kp < 4; ++kp) {
    int ko = (kp * 32 + l4 * 8) * 2;
    bf16x8 pa[2], vb[8];
#pragma unroll
    for (int mf = 0; mf < 2; ++mf) {
      int hh = wid * 32 + mf * 16 + l15;
      pa[mf] = *(const bf16x8*)((const char*)qs + hh * 256 + (ko ^ ((hh & 7) << 4)));
    }
#pragma unroll
    for (int nf = 0; nf < 8; ++nf) {
      int w = nf * 16 + l15;
      int chunk = (ko >> 4) ^ (w & 7) ^ ((w >> 3) & 7);
      vb[nf] = *(const bf16x8*)((const char*)ks + w * 256 + (chunk << 4));
    }
#pragma unroll
    for (int mf = 0; mf < 2; ++mf)
#pragma unroll
      for (int nf = 0; nf < 8; ++nf)
        o[mf][nf] =
            __builtin_amdgcn_mfma_f32_16x16x32_bf16(pa[mf], vb[nf], o[mf][nf], 0, 0, 0);
  }
  float* ob = out + (size_t)bc * 16384;
#pragma unroll
  for (int mf = 0; mf < 2; ++mf)
#pragma unroll
    for (int r = 0; r < 4; ++r) {
      int hh = wid * 32 + mf * 16 + l4 * 4 + r;
#pragma unroll
      for (int nf = 0; nf < 8; ++nf) {
        int w = nf * 16 + l15;
        ob[hh * 128 + w] = o[mf][nf][r];
      }
    }
}

// ---------------------------------------------------------------------------
extern "C" void kernel_launch(void* const* d_in, const int* in_sizes, int n_in,
                              void* d_out, int out_size, void* d_ws, size_t ws_size,
                              hipStream_t stream) {
  const float* x = (const float*)d_in[0];
  const float* wq = (const float*)d_in[1];
  const float* bq = (const float*)d_in[2];
  const float* wk = (const float*)d_in[3];
  const float* bk = (const float*)d_in[4];
  const float* wv = (const float*)d_in[5];
  const float* bv = (const float*)d_in[6];

  // ws layout: x_t (128 MiB) | Wt (3.375 MiB) | v (128 MiB)  => ~259.4 MiB.
  // q,k (bf16) live inside d_out: each (b,c) region is 64 KiB f32; q occupies
  // bytes [0,32768), k bytes [32768,65536) until attn consumes them.
  char* ws = (char*)d_ws;
  unsigned short* xt = (unsigned short*)ws;
  unsigned short* wt = (unsigned short*)(ws + 134217728);
  unsigned short* vbuf = (unsigned short*)(ws + 134217728 + 3538944);

  prep_w<<<6912, 256, 0, stream>>>(wq, wk, wv, wt);
  prep_x<<<dim3(4, 128, 16), 256, 0, stream>>>(x, xt);
  conv_qkv<<<6144, 256, 0, stream>>>(xt, wt, bq, bk, bv, (unsigned short*)d_out,
                                     vbuf);
  attn_kernel<<<dim3(256, 16), 256, 0, stream>>>((const unsigned short*)d_out, vbuf,
                                                 (float*)d_out);
}